// Round 6
// baseline (248.968 us; speedup 1.0000x reference)
//
#include <hip/hip_runtime.h>

// IntegerNeuron: T-step integrate-fire scan over [T,B,C,H,W].
// T=8, B=32, C=128, H=32, W=32. Memory-bound: 128 MiB in + 128 MiB out.
//
// Numerics: bit-exact vs fp32 reference (hard threshold). Reference order:
//   drive = x*tau; mem = (mem + drive) + bias_scaled;
//   spike = mem >= vth_scaled; mem -= spike*vth_scaled.
// tau==4.0 (pow2) => x*tau exact => FMA contraction bit-identical.
// jnp.round == rintf (half-to-even).
//
// History:
//  R1 nt-builtin stores: 92 us (worse), FETCH unchanged.
//  R2 empty-asm pin: null (VGPR CSV later proven unreliable).
//  R3 asm loads "=v": VM fault (dest aliased later load's offset reg).
//  R4 asm loads "=&v", 8-deep burst, ONE vmcnt(0), plain stores: 89-92 us
//     => raw MLP is not the limiter (or burst oversubscribes queues).
//  R5 depth-1 + `sc0 sc1 nt` stores: 79.4 us (best). FETCH still 64 MiB.
//     Same profile: fillBufferAligned = 6.7 TB/s @ 9.5% occupancy => the
//     memory system serves ~2.7x our rate for pure writes.
//
// R6 theory: every fast variant so far waits vmcnt(0) per iteration, which
// (vmcnt counts stores, in-order retirement) also drains the PREVIOUS
// iteration's store ack — expensive for system-scope sc0 sc1 stores. R4
// removed drains but confounded with an 8-deep load burst + plain stores.
// This kernel: 3-deep load pipeline, hand-counted waits that NEVER retire a
// store (vmcnt(N) = #vmem ops issued after the target load), sc0 sc1 nt
// stores. Wait counts for issue order
//   L0 L1 L2 [w0] S0 L3 [w1] S1 L4 [w2] S2 L5 [w3] S3 L6 [w4] S4 L7
//   [w5] S5 [w6] S6 [w7] S7 :
//   w0=2 w1=3 w2=4 w3=4 w4=4 w5=4 w6=3 w7=2.
// Each wait carries its load's reg as "+v" (data-dep fence, skill rule #18)
// + sched_barrier(0). Early-clobber "=&v" on all load dests (R3 lesson).
// Load/store share the same offset VGPRs (slice stride 16 MiB = 0x1000000;
// max offset < 2^27, fits the 32-bit voffset form proven in R4/R5).

typedef float f4 __attribute__((ext_vector_type(4)));

constexpr int T_STEPS = 8;
constexpr int NB = 32, NC = 128, NH = 32, NW = 32;
constexpr int NSP = NB * NC * NH * NW;   // 4,194,304 spatial positions
constexpr int N4  = NSP / 4;             // 1,048,576 float4 positions
constexpr int HW4 = (NH * NW) / 4;       // 256 float4 per (b,c) plane == blockDim

__global__ __launch_bounds__(256) void IntegerNeuron_84842783965742_kernel(
    const f4*    __restrict__ x,            // [T, B, C, H, W] as float4
    const float* __restrict__ prev_scale,   // [C]
    const float* __restrict__ prev_bias,    // [C]
    const float* __restrict__ vth,          // scalar
    const int*   __restrict__ tau,          // scalar int
    const int*   __restrict__ is_first,     // scalar int
    f4*          __restrict__ out)          // [T, B, C, H, W] as float4
{
    const int i = blockIdx.x * blockDim.x + threadIdx.x;   // float4 index
    const int c = blockIdx.x % NC;  // uniform per block (blockDim == HW4)

    const float tau_f = (float)tau[0];
    const float denom = prev_scale[c] + 1e-12f;
    const float bs = rintf(prev_bias[c] * tau_f / denom);  // bias_scaled[c]
    const float vs = rintf(vth[0] * tau_f / denom);        // vth_scaled[c]
    const float mul = is_first[0] ? 1.0f : tau_f;          // drive multiplier

    const unsigned int b0 = (unsigned int)i * 16u;         // byte offset, slice 0
    const unsigned int o0 = b0 + 0x0000000u, o1 = b0 + 0x1000000u;
    const unsigned int o2 = b0 + 0x2000000u, o3 = b0 + 0x3000000u;
    const unsigned int o4 = b0 + 0x4000000u, o5 = b0 + 0x5000000u;
    const unsigned int o6 = b0 + 0x6000000u, o7 = b0 + 0x7000000u;

    f4 x0, x1, x2, x3, x4, x5, x6, x7;
    float m0 = 0.0f, m1 = 0.0f, m2 = 0.0f, m3 = 0.0f;      // mem in VGPRs
    f4 sp;

#define LOADK(xk, ok)                                                       \
    asm volatile("global_load_dwordx4 %0, %1, %2"                           \
                 : "=&v"(xk) : "v"(ok), "s"(x))

#define WAITK(xk, n)                                                        \
    asm volatile("s_waitcnt vmcnt(" #n ")" : "+v"(xk));                     \
    __builtin_amdgcn_sched_barrier(0)

#define STOREK(ok)                                                          \
    asm volatile("global_store_dwordx4 %0, %1, %2 sc0 sc1 nt"               \
                 :: "v"(ok), "v"(sp), "s"(out))

#define COMPUTE(xv)                                                         \
    do { /* mem = (mem + x*tau) + bias_scaled — reference association */    \
        m0 = (m0 + (xv).x * mul) + bs;                                      \
        m1 = (m1 + (xv).y * mul) + bs;                                      \
        m2 = (m2 + (xv).z * mul) + bs;                                      \
        m3 = (m3 + (xv).w * mul) + bs;                                      \
        sp.x = (m0 >= vs) ? 1.0f : 0.0f;                                    \
        sp.y = (m1 >= vs) ? 1.0f : 0.0f;                                    \
        sp.z = (m2 >= vs) ? 1.0f : 0.0f;                                    \
        sp.w = (m3 >= vs) ? 1.0f : 0.0f;                                    \
        /* soft reset: spike and vs integer-valued, product exact */        \
        m0 -= sp.x * vs;                                                    \
        m1 -= sp.y * vs;                                                    \
        m2 -= sp.z * vs;                                                    \
        m3 -= sp.w * vs;                                                    \
    } while (0)

    // Prologue: 3 loads in flight.
    LOADK(x0, o0);
    LOADK(x1, o1);
    LOADK(x2, o2);

    WAITK(x0, 2); COMPUTE(x0); STOREK(o0); LOADK(x3, o3);
    WAITK(x1, 3); COMPUTE(x1); STOREK(o1); LOADK(x4, o4);
    WAITK(x2, 4); COMPUTE(x2); STOREK(o2); LOADK(x5, o5);
    WAITK(x3, 4); COMPUTE(x3); STOREK(o3); LOADK(x6, o6);
    WAITK(x4, 4); COMPUTE(x4); STOREK(o4); LOADK(x7, o7);
    WAITK(x5, 4); COMPUTE(x5); STOREK(o5);
    WAITK(x6, 3); COMPUTE(x6); STOREK(o6);
    WAITK(x7, 2); COMPUTE(x7); STOREK(o7);

#undef LOADK
#undef WAITK
#undef STOREK
#undef COMPUTE
}

extern "C" void kernel_launch(void* const* d_in, const int* in_sizes, int n_in,
                              void* d_out, int out_size, void* d_ws, size_t ws_size,
                              hipStream_t stream) {
    const f4*    x          = (const f4*)d_in[0];
    const float* prev_scale = (const float*)d_in[1];
    const float* prev_bias  = (const float*)d_in[2];
    const float* vth        = (const float*)d_in[3];
    const int*   tau        = (const int*)d_in[4];
    const int*   is_first   = (const int*)d_in[5];
    f4*          out        = (f4*)d_out;

    dim3 block(256);
    dim3 grid(N4 / 256);   // 4096 blocks
    IntegerNeuron_84842783965742_kernel<<<grid, block, 0, stream>>>(
        x, prev_scale, prev_bias, vth, tau, is_first, out);
}